// Round 4
// baseline (785.816 us; speedup 1.0000x reference)
//
#include <hip/hip_runtime.h>
#include <hip/hip_cooperative_groups.h>
#include <stdint.h>

// Hard voxelization, MI355X. f32x4 points -> f32 concat out:
//   voxels[60000,32,4], coors[60000,3](z,y,x), npv[60000], voxel_num[1].
//
// R15 forensics: bitmap fast-path landed (passed) yet dur_us 136->140 while
// kernel-side work dropped by ~30us of scattered probing. Two rounds of large
// device-time savings with ~0 total delta => dur_us is dominated by LAUNCH
// overhead, not kernel execution: 7 dispatches x ~15us gap ~= the unexplained
// ~105us (my kernels sum to ~30-35us; top-5 is 100% harness fill @45us).
// R16: fuse the whole pipeline into ONE cooperative kernel with grid.sync()
// stage boundaries (init -> build_early -> {build_late || flags-early} ->
// scan(block0) -> finish+drain -> emit). 5 syncs in fast mode. 768 blocks x
// 256 thr with __launch_bounds__(256,4) guarantees co-residency (4 blk/CU min
// x 256 CUs), so grid.sync is safe. Host falls back to the proven 7-kernel
// pipeline if hipLaunchCooperativeKernel is rejected.

#define GX 1024
#define GY 1024
#define GZ 40
#define NVOXEL (GX * GY * GZ)                 // 41,943,040
#define MAXV 60000
#define MAXP 32
#define HBITS 21
#define HSIZE (1u << HBITS)
#define HMASK (HSIZE - 1u)
#define CANDBIT (1 << 30)
#define FLATMASK (CANDBIT - 1)
#define TB 256
#define KEARLY 131072
#define NBE (KEARLY / TB)                     // 512 early blocks
#define NBITW (NVOXEL / 32)                   // 1,310,720 bitmap words
#define GRID_BLKS 768                         // 3/CU worst case; <= capacity
#define EMPTY64 0xFFFFFFFFFFFFFFFFull

#define OFF_COORS ((size_t)MAXV * MAXP * 4)            // 7,680,000
#define OFF_NPV   (OFF_COORS + (size_t)MAXV * 3)       // 7,860,000
#define OFF_VNUM  (OFF_NPV + (size_t)MAXV)             // 7,920,000

typedef unsigned long long u64;
namespace cg = cooperative_groups;

__device__ __forceinline__ unsigned hashf(int flat) {
    return ((unsigned)flat * 2654435761u) >> (32 - HBITS);
}

__device__ __forceinline__ int voxel_flat(float4 pt) {
    // identical IEEE f32 math to reference
    float fx = floorf((pt.x + 51.2f) / 0.1f);
    float fy = floorf((pt.y + 51.2f) / 0.1f);
    float fz = floorf((pt.z + 5.0f) / 0.2f);
    int cx = (int)fx, cy = (int)fy, cz = (int)fz;
    bool valid = (fx >= 0.f) & (cx < GX) & (fy >= 0.f) & (cy < GY) & (fz >= 0.f) & (cz < GZ);
    return valid ? (cx * GY + cy) * GZ + cz : -1;
}

// ---- exact insert path (R12 semantics): 1 CAS typ.; returns pflat value ----
__device__ __forceinline__ int build_insert(int p, int flat, u64* __restrict__ h64,
                                            unsigned char* __restrict__ contested,
                                            int* __restrict__ nvox,
                                            unsigned* __restrict__ bitmap,
                                            int count_wins) {
    u64 want = ((u64)(unsigned)flat << 32) | (unsigned)p;
    unsigned slot = hashf(flat);
    int cand = 0, won = 0;
    for (int probe = 0; probe < 4096; probe++) {          // bounded: hang-proof
        u64 cur = atomicCAS(&h64[slot], EMPTY64, want);
        if (cur == EMPTY64) { cand = 1; won = 1; break; } // insert winner (new voxel)
        if ((unsigned)(cur >> 32) == (unsigned)flat) {    // existing voxel
            if ((unsigned)cur > (unsigned)p) {
                u64 old = atomicMin(&h64[slot], want);    // key equal -> compares rep
                unsigned oldrep = (unsigned)old;
                if (oldrep > (unsigned)p) {               // we really lowered it
                    contested[oldrep] = 1;                // previous holder dethroned
                    cand = 1;
                }
            }
            break;
        }
        slot = (slot + 1u) & HMASK;
    }
    if (won) {
        atomicOr(&bitmap[(unsigned)flat >> 5], 1u << (flat & 31));  // voxel present
        if (count_wins) atomicAdd(nvox, 1);               // wave-aggregated
    }
    return flat | (cand ? CANDBIT : 0);
}

// ---- dup registration: flat -> h64 rep -> popcount rank -> dupcnt/list ----
__device__ __forceinline__ void register_dup(int flat, int i,
                                             const u64* __restrict__ h64,
                                             const u64* __restrict__ flagbits,
                                             const int* __restrict__ partials,
                                             int* __restrict__ dupcnt,
                                             int* __restrict__ list) {
    unsigned slot = hashf(flat);
    unsigned rep = 0xFFFFFFFFu;
    for (int probe = 0; probe < 4096; probe++) {     // read-only, cache-hot
        u64 cur = h64[slot];
        if ((unsigned)(cur >> 32) == (unsigned)flat) { rep = (unsigned)cur; break; }
        if (cur == EMPTY64) break;
        slot = (slot + 1u) & HMASK;
    }
    if (rep == 0xFFFFFFFFu) return;
    int br = (int)(rep >> 8);                        // rep's 256-block
    int lb = (int)(rep & 255u);
    int dvid = partials[br];
    int wb = br * 4, nw = lb >> 6;
    for (int q = 0; q < nw; q++) dvid += (int)__popcll(flagbits[wb + q]);
    int tail = lb & 63;
    if (tail) dvid += (int)__popcll(flagbits[wb + nw] & ((1ull << tail) - 1ull));
    if (dvid < MAXV) {
        int pos = atomicAdd(&dupcnt[dvid], 1);
        if (pos < MAXP - 1) list[dvid * (MAXP - 1) + pos] = i;
    }
}

// =================== fused cooperative kernel ===================
__global__ __launch_bounds__(TB, 4) void k_all(const float4* __restrict__ pts,
                                               int n, int nbp,
                                               u64* __restrict__ h64,
                                               unsigned* __restrict__ bitmap,
                                               unsigned char* __restrict__ contested,
                                               int* __restrict__ pflat,
                                               u64* __restrict__ flagbits,
                                               int* __restrict__ partials,
                                               int* __restrict__ repidx,
                                               int* __restrict__ dupcnt,
                                               int* __restrict__ list,
                                               u64* __restrict__ latedup,
                                               int* __restrict__ nvox,
                                               unsigned* __restrict__ dcnt,
                                               float4* __restrict__ outVox,
                                               float* __restrict__ oF) {
    cg::grid_group grid = cg::this_grid();
    const int t = threadIdx.x;
    const int gid = blockIdx.x * TB + t;
    const int gsz = gridDim.x * TB;

    // ---- S0 init ----
    if (gid == 0) { *nvox = 0; *dcnt = 0; }
    for (int j = gid; j < (int)HSIZE; j += gsz) h64[j] = EMPTY64;
    for (int j = gid; j < NBITW; j += gsz) bitmap[j] = 0u;
    {
        int nw = (n + 3) / 4;
        unsigned* c4 = (unsigned*)contested;
        for (int j = gid; j < nw; j += gsz) c4[j] = 0;
    }
    for (int j = gid; j < MAXV; j += gsz) { dupcnt[j] = 0; repidx[j] = -1; }
    for (int j = gid; j < MAXV * 3; j += gsz) oF[OFF_COORS + j] = 0.f;
    for (int j = gid; j < nbp; j += gsz) partials[j] = 0;
    __threadfence();
    grid.sync();

    // ---- S1 build_early: first min(n,KEARLY) pts, full insert + bitmap ----
    {
        int nE = n < KEARLY ? n : KEARLY;
        for (int p = gid; p < nE; p += gsz) {
            float4 pt = pts[p];
            int flat = voxel_flat(pt);
            if (flat < 0) { pflat[p] = -1; continue; }
            pflat[p] = build_insert(p, flat, h64, contested, nvox, bitmap, 1);
        }
    }
    __threadfence();
    grid.sync();

    const bool fast = (*nvox >= MAXV);            // grid-uniform after sync
    const int npbF = fast ? (nbp < NBE ? nbp : NBE) : nbp;

    // ---- S2 build_late (+ flags-early in fast mode; both depend on S1 only) ----
    if (fast) {
        // >=MAXV voxels already exist with reps < KEARLY <= p: a voxel first
        // seen here would get vid >= MAXV => dropped. Only dup-of-early
        // matters; bitmap answers membership exactly. No pflat/h64 traffic.
        for (int p = KEARLY + gid; p < n; p += gsz) {
            float4 pt = pts[p];
            int flat = voxel_flat(pt);
            if (flat < 0) continue;
            unsigned wv = bitmap[(unsigned)flat >> 5];
            if (wv & (1u << (flat & 31))) {
                unsigned pos = atomicAdd(dcnt, 1u);
                if (pos < (unsigned)(n - KEARLY))
                    latedup[pos] = ((u64)(unsigned)flat << 32) | (unsigned)p;
            }
        }
        // flags for early point-blocks (late points can never be reps)
        for (int pb = blockIdx.x; pb < npbF; pb += gridDim.x) {
            int i = pb * TB + t;
            int pred = 0;
            if (i < n) {
                int pf = pflat[i];
                pred = (pf >= 0) && (pf & CANDBIT) && !contested[i];
            }
            u64 m = __ballot(pred);
            if ((t & 63) == 0) {
                flagbits[pb * 4 + (t >> 6)] = m;
                atomicAdd(&partials[pb], (int)__popcll(m));
            }
        }
        __threadfence();
        grid.sync();
    } else {
        // fallback: exact R12 insert for late points
        for (int p = KEARLY + gid; p < n; p += gsz) {
            float4 pt = pts[p];
            int flat = voxel_flat(pt);
            if (flat < 0) { pflat[p] = -1; continue; }
            pflat[p] = build_insert(p, flat, h64, contested, nvox, bitmap, 0);
        }
        __threadfence();
        grid.sync();
        // flags for ALL point-blocks
        for (int pb = blockIdx.x; pb < nbp; pb += gridDim.x) {
            int i = pb * TB + t;
            int pred = 0;
            if (i < n) {
                int pf = pflat[i];
                pred = (pf >= 0) && (pf & CANDBIT) && !contested[i];
            }
            u64 m = __ballot(pred);
            if ((t & 63) == 0) {
                flagbits[pb * 4 + (t >> 6)] = m;
                atomicAdd(&partials[pb], (int)__popcll(m));
            }
        }
        __threadfence();
        grid.sync();
    }

    // ---- S3 scan: block 0 only; exclusive prefix over nbp partials ----
    if (blockIdx.x == 0) {
        __shared__ int sh[TB];
        int E = (nbp + TB - 1) / TB;              // 19 at n=1.2M
        int s = 0;
        for (int k = 0; k < E; k++) {
            int idx = t * E + k;
            if (idx < nbp) s += partials[idx];
        }
        sh[t] = s;
        __syncthreads();
        for (int off = 1; off < TB; off <<= 1) {
            int add = (t >= off) ? sh[t - off] : 0;
            __syncthreads();
            sh[t] += add;
            __syncthreads();
        }
        int run = sh[t] - s;                      // exclusive base
        for (int k = 0; k < E; k++) {
            int idx = t * E + k;
            if (idx < nbp) { int tmp = partials[idx]; partials[idx] = run; run += tmp; }
        }
        if (t == TB - 1) {
            int total = sh[TB - 1];
            if (total > MAXV) total = MAXV;
            oF[OFF_VNUM] = (float)total;          // voxel_num
        }
    }
    __threadfence();
    grid.sync();

    // ---- S4 finish: reps->coors/repidx, per-point dups; + latedup drain ----
    for (int pb = blockIdx.x; pb < npbF; pb += gridDim.x) {
        int i = pb * TB + t;
        if (i >= n) continue;
        int lane = t & 63, w = t >> 6;
        u64 w0 = flagbits[pb * 4 + 0];
        u64 w1 = flagbits[pb * 4 + 1];
        u64 w2 = flagbits[pb * 4 + 2];
        u64 w3 = flagbits[pb * 4 + 3];
        u64 myw = (w == 0) ? w0 : (w == 1) ? w1 : (w == 2) ? w2 : w3;
        int bit = (int)((myw >> lane) & 1);
        int pf = pflat[i];
        if (bit) {                                           // first occurrence (rep)
            int wbase = (w > 0 ? __popcll(w0) : 0) + (w > 1 ? __popcll(w1) : 0)
                      + (w > 2 ? __popcll(w2) : 0);
            int vid = partials[pb] + wbase + (int)__popcll(myw & ((1ull << lane) - 1ull));
            if (vid < MAXV) {
                int flat = pf & FLATMASK;
                int zc = flat % GZ;
                int t2 = flat / GZ;
                int yc = t2 % GY;
                int xc = t2 / GY;
                size_t cOff = OFF_COORS + (size_t)vid * 3;
                oF[cOff + 0] = (float)zc;
                oF[cOff + 1] = (float)yc;
                oF[cOff + 2] = (float)xc;
                repidx[vid] = i;
            }
        } else if (pf >= 0) {                                // non-rep valid
            register_dup(pf & FLATMASK, i, h64, flagbits, partials, dupcnt, list);
        }
    }
    {
        unsigned cnt = *dcnt;                                // 0 in fallback
        unsigned cap = (n > KEARLY) ? (unsigned)(n - KEARLY) : 0u;
        if (cnt > cap) cnt = cap;
        for (unsigned idx = (unsigned)gid; idx < cnt; idx += (unsigned)gsz) {
            u64 e = latedup[idx];
            register_dup((int)(e >> 32), (int)(unsigned)e,
                         h64, flagbits, partials, dupcnt, list);
        }
    }
    __threadfence();
    grid.sync();

    // ---- S5 emit: thread-per-row, fully coalesced voxels store; npv ----
    for (int g2 = gid; g2 < MAXV * MAXP; g2 += gsz) {
        int vid = g2 >> 5;
        int r = g2 & 31;
        int ri = repidx[vid];
        int dc = dupcnt[vid];
        int d = dc < (MAXP - 1) ? dc : (MAXP - 1);
        int m = (ri >= 0) ? (1 + d) : 0;
        if (r == 0) oF[OFF_NPV + vid] = (float)m;
        float4 row = make_float4(0.f, 0.f, 0.f, 0.f);
        if (r == 0 && m > 0) {
            row = pts[ri];                               // rep = provably min index
        } else if (r < m) {                              // dup rows, ascending index
            const int* lst = &list[vid * (MAXP - 1)];
            int target = r - 1, pick = -1;
            for (int a = 0; a < d; a++) {
                int e = lst[a];
                int rk = 0;
                for (int bq = 0; bq < d; bq++) rk += (lst[bq] < e);
                if (rk == target) pick = e;
            }
            row = pts[pick];
        }
        outVox[(size_t)vid * MAXP + r] = row;            // coalesced 16B stores
    }
}

// =================== legacy 7-kernel fallback path ===================
__global__ void k_init(u64* __restrict__ h64, unsigned char* __restrict__ contested,
                       int* __restrict__ dupcnt, int* __restrict__ repidx,
                       int n, float* __restrict__ oF, int* __restrict__ nvox,
                       unsigned* __restrict__ bitmap, unsigned* __restrict__ dcnt) {
    int i = blockIdx.x * blockDim.x + threadIdx.x;
    int stride = gridDim.x * blockDim.x;
    if (i == 0) { *nvox = 0; *dcnt = 0; }
    for (int j = i; j < (int)HSIZE; j += stride) h64[j] = EMPTY64;
    for (int j = i; j < NBITW; j += stride) bitmap[j] = 0u;
    int nw = (n + 3) / 4;
    unsigned* c4 = (unsigned*)contested;
    for (int j = i; j < nw; j += stride) c4[j] = 0;
    for (int j = i; j < MAXV; j += stride) { dupcnt[j] = 0; repidx[j] = -1; }
    for (int j = i; j < MAXV * 3; j += stride) oF[OFF_COORS + j] = 0.f;
}

__global__ __launch_bounds__(TB) void k_build_early(const float4* __restrict__ pts, int nE,
                                                    u64* __restrict__ h64,
                                                    int* __restrict__ pflat,
                                                    unsigned char* __restrict__ contested,
                                                    int* __restrict__ nvox,
                                                    unsigned* __restrict__ bitmap) {
    int p = blockIdx.x * blockDim.x + threadIdx.x;
    if (p >= nE) return;
    float4 pt = pts[p];
    int flat = voxel_flat(pt);
    if (flat < 0) { pflat[p] = -1; return; }
    pflat[p] = build_insert(p, flat, h64, contested, nvox, bitmap, 1);
}

__global__ __launch_bounds__(TB) void k_build_late(const float4* __restrict__ pts, int n,
                                                   u64* __restrict__ h64,
                                                   int* __restrict__ pflat,
                                                   unsigned char* __restrict__ contested,
                                                   int* __restrict__ nvox,
                                                   unsigned* __restrict__ bitmap,
                                                   u64* __restrict__ latedup,
                                                   unsigned* __restrict__ dcnt) {
    int p = KEARLY + blockIdx.x * blockDim.x + threadIdx.x;
    if (p >= n) return;
    float4 pt = pts[p];
    int flat = voxel_flat(pt);
    if (*nvox < MAXV) {
        if (flat < 0) { pflat[p] = -1; return; }
        pflat[p] = build_insert(p, flat, h64, contested, nvox, bitmap, 0);
        return;
    }
    if (flat < 0) return;
    unsigned w = bitmap[(unsigned)flat >> 5];
    if (w & (1u << (flat & 31))) {
        unsigned pos = atomicAdd(dcnt, 1u);
        if (pos < (unsigned)(n - KEARLY))
            latedup[pos] = ((u64)(unsigned)flat << 32) | (unsigned)p;
    }
}

__global__ __launch_bounds__(TB) void k_flags(const int* __restrict__ pflat,
                                              const unsigned char* __restrict__ contested,
                                              int n, u64* __restrict__ flagbits,
                                              int* __restrict__ partials,
                                              const int* __restrict__ nvox) {
    __shared__ int ws[4];
    int b = blockIdx.x, t = threadIdx.x;
    int i = b * TB + t;
    int fastmode = (*nvox >= MAXV);
    int pred = 0;
    if (i < n && (b < NBE || !fastmode)) {
        int pf = pflat[i];
        pred = (pf >= 0) && (pf & CANDBIT) && !contested[i];
    }
    u64 m = __ballot(pred);
    int w = t >> 6, lane = t & 63;
    if (lane == 0) { flagbits[b * 4 + w] = m; ws[w] = __popcll(m); }
    __syncthreads();
    if (t == 0) partials[b] = ws[0] + ws[1] + ws[2] + ws[3];
}

__global__ __launch_bounds__(1024) void k_scan(int* __restrict__ partials, int npart,
                                               float* __restrict__ oF) {
    __shared__ int sh[1024];
    int t = threadIdx.x;
    int v[5];
    int s = 0;
    #pragma unroll
    for (int k = 0; k < 5; k++) {
        int idx = t * 5 + k;
        v[k] = (idx < npart) ? partials[idx] : 0;
        s += v[k];
    }
    sh[t] = s;
    __syncthreads();
    for (int off = 1; off < 1024; off <<= 1) {
        int add = (t >= off) ? sh[t - off] : 0;
        __syncthreads();
        sh[t] += add;
        __syncthreads();
    }
    int run = sh[t] - s;
    #pragma unroll
    for (int k = 0; k < 5; k++) {
        int idx = t * 5 + k;
        if (idx < npart) partials[idx] = run;
        run += v[k];
    }
    if (t == 1023) {
        int total = sh[1023];
        if (total > MAXV) total = MAXV;
        oF[OFF_VNUM] = (float)total;
    }
}

__global__ __launch_bounds__(TB) void k_finish(const u64* __restrict__ flagbits,
                                               const int* __restrict__ partials,
                                               const int* __restrict__ pflat,
                                               const u64* __restrict__ h64,
                                               int* __restrict__ repidx,
                                               int* __restrict__ dupcnt,
                                               int* __restrict__ list, int n,
                                               float* __restrict__ oF,
                                               const int* __restrict__ nvox,
                                               const u64* __restrict__ latedup,
                                               const unsigned* __restrict__ dcnt) {
    int b = blockIdx.x, t = threadIdx.x;
    int fastmode = (*nvox >= MAXV);
    if (fastmode && b >= NBE) {
        unsigned cnt = *dcnt;
        unsigned cap = (unsigned)(n - KEARLY);
        if (cnt > cap) cnt = cap;
        unsigned idx = (unsigned)(b - NBE) * TB + t;
        if (idx < cnt) {
            u64 e = latedup[idx];
            register_dup((int)(e >> 32), (int)(unsigned)e,
                         h64, flagbits, partials, dupcnt, list);
        }
        return;
    }
    int i = b * TB + t;
    if (i >= n) return;
    int lane = t & 63, w = t >> 6;
    u64 w0 = flagbits[b * 4 + 0];
    u64 w1 = flagbits[b * 4 + 1];
    u64 w2 = flagbits[b * 4 + 2];
    u64 w3 = flagbits[b * 4 + 3];
    u64 myw = (w == 0) ? w0 : (w == 1) ? w1 : (w == 2) ? w2 : w3;
    int bit = (int)((myw >> lane) & 1);
    int pf = pflat[i];
    if (bit) {
        int wbase = (w > 0 ? __popcll(w0) : 0) + (w > 1 ? __popcll(w1) : 0)
                  + (w > 2 ? __popcll(w2) : 0);
        int vid = partials[b] + wbase + (int)__popcll(myw & ((1ull << lane) - 1ull));
        if (vid < MAXV) {
            int flat = pf & FLATMASK;
            int zc = flat % GZ;
            int t2 = flat / GZ;
            int yc = t2 % GY;
            int xc = t2 / GY;
            size_t cOff = OFF_COORS + (size_t)vid * 3;
            oF[cOff + 0] = (float)zc;
            oF[cOff + 1] = (float)yc;
            oF[cOff + 2] = (float)xc;
            repidx[vid] = i;
        }
    } else if (pf >= 0) {
        register_dup(pf & FLATMASK, i, h64, flagbits, partials, dupcnt, list);
    }
}

__global__ __launch_bounds__(TB) void k_emit(const float4* __restrict__ pts,
                                             const int* __restrict__ repidx,
                                             const int* __restrict__ dupcnt,
                                             const int* __restrict__ list,
                                             float4* __restrict__ outVox,
                                             float* __restrict__ oF) {
    int gid = blockIdx.x * TB + threadIdx.x;
    int vid = gid >> 5;
    if (vid >= MAXV) return;
    int r = gid & 31;
    int ri = repidx[vid];
    int dc = dupcnt[vid];
    int d = dc < (MAXP - 1) ? dc : (MAXP - 1);
    int m = (ri >= 0) ? (1 + d) : 0;
    if (r == 0) oF[OFF_NPV + vid] = (float)m;
    float4 row = make_float4(0.f, 0.f, 0.f, 0.f);
    if (r == 0 && m > 0) {
        row = pts[ri];
    } else if (r < m) {
        const int* lst = &list[vid * (MAXP - 1)];
        int target = r - 1, pick = -1;
        for (int a = 0; a < d; a++) {
            int e = lst[a];
            int rk = 0;
            for (int bq = 0; bq < d; bq++) rk += (lst[bq] < e);
            if (rk == target) pick = e;
        }
        row = pts[pick];
    }
    outVox[(size_t)vid * MAXP + r] = row;
}

extern "C" void kernel_launch(void* const* d_in, const int* in_sizes, int n_in,
                              void* d_out, int out_size, void* d_ws, size_t ws_size,
                              hipStream_t stream) {
    int n = in_sizes[0] / 4;                       // 1,200,000
    const float4* pts = (const float4*)d_in[0];

    int tb = TB;
    int nbp = (n + tb - 1) / tb;                   // 4688
    int nwords = nbp * 4;

    // ws layout, ~45 MB
    char* base = (char*)d_ws;
    size_t o = 0;
    int* partials = (int*)(base + o);  o += ((size_t)nbp * 4 + 255) & ~(size_t)255;
    int* dupcnt   = (int*)(base + o);  o += (size_t)MAXV * 4;
    int* repidx   = (int*)(base + o);  o += (size_t)MAXV * 4;
    o = (o + 255) & ~(size_t)255;
    u64* flagbits = (u64*)(base + o);  o += (size_t)nwords * 8;
    o = (o + 255) & ~(size_t)255;
    unsigned char* contested = (unsigned char*)(base + o);  o += ((size_t)n + 255) & ~(size_t)255;
    u64* h64      = (u64*)(base + o);  o += (size_t)HSIZE * 8;
    int* pflat    = (int*)(base + o);  o += (size_t)n * 4;
    int* list     = (int*)(base + o);  o += (size_t)MAXV * (MAXP - 1) * 4;
    o = (o + 255) & ~(size_t)255;
    unsigned* bitmap = (unsigned*)(base + o);  o += (size_t)NBITW * 4;
    o = (o + 255) & ~(size_t)255;
    u64* latedup  = (u64*)(base + o);  o += (size_t)(n > KEARLY ? n - KEARLY : 1) * 8;
    o = (o + 255) & ~(size_t)255;
    int* nvox     = (int*)(base + o);  o += 256;
    unsigned* dcnt = (unsigned*)(base + o);  o += 256;

    float* oF = (float*)d_out;
    float4* outVox = (float4*)d_out;

    // fused cooperative launch (single dispatch, 5 grid syncs)
    void* args[] = { (void*)&pts, (void*)&n, (void*)&nbp, (void*)&h64,
                     (void*)&bitmap, (void*)&contested, (void*)&pflat,
                     (void*)&flagbits, (void*)&partials, (void*)&repidx,
                     (void*)&dupcnt, (void*)&list, (void*)&latedup,
                     (void*)&nvox, (void*)&dcnt, (void*)&outVox, (void*)&oF };
    hipError_t err = hipLaunchCooperativeKernel((const void*)k_all,
                                                dim3(GRID_BLKS), dim3(TB),
                                                args, 0, stream);
    if (err == hipSuccess) return;

    // fallback: proven 7-kernel pipeline (R15)
    int nE = n < KEARLY ? n : KEARLY;
    int nbE = (nE + tb - 1) / tb;
    int nL = n - nE;

    k_init<<<2048, tb, 0, stream>>>(h64, contested, dupcnt, repidx, n, oF, nvox,
                                    bitmap, dcnt);
    k_build_early<<<nbE, tb, 0, stream>>>(pts, nE, h64, pflat, contested, nvox, bitmap);
    if (nL > 0)
        k_build_late<<<(nL + tb - 1) / tb, tb, 0, stream>>>(pts, n, h64, pflat,
                                                            contested, nvox, bitmap,
                                                            latedup, dcnt);
    k_flags<<<nbp, tb, 0, stream>>>(pflat, contested, n, flagbits, partials, nvox);
    k_scan<<<1, 1024, 0, stream>>>(partials, nbp, oF);
    k_finish<<<nbp, tb, 0, stream>>>(flagbits, partials, pflat, h64, repidx, dupcnt,
                                     list, n, oF, nvox, latedup, dcnt);
    k_emit<<<(MAXV * MAXP + tb - 1) / tb, tb, 0, stream>>>(pts, repidx, dupcnt, list,
                                                           outVox, oF);
}

// Round 5
// 371.891 us; speedup vs baseline: 2.1130x; 2.1130x over previous
//
#include <hip/hip_runtime.h>
#include <stdint.h>

// Hard voxelization, MI355X. f32x4 points -> f32 concat out:
//   voxels[60000,32,4], coors[60000,3](z,y,x), npv[60000], voxel_num[1].
//
// R16 forensics: cooperative fuse correct but cg::grid.sync() costs ~140us
// EACH on gfx950 (k_all 728us, VALUBusy 0.7%, occupancy 37% = resident+idle;
// stage work is ~35-40us). R17: keep the fusion, hand-roll the barrier:
// two-level agent-scope barrier (16 padded sub-counters x 48 arrivals ->
// master -> release flag, s_sleep(4) spin). Single-use instances zeroed by
// k_init (no sense-reversal). __threadfence + __hip_atomic ACQ_REL/ACQUIRE
// give the cross-XCD happens-before (guide G16). 2 dispatches: k_init
// (normal) + k_rest (cooperative, 3 barriers fast mode). Cooperative launch
// guarantees co-residency; host falls back to the proven R15 7-kernel path
// if rejected. Fill (45us, harness re-poison) is the fixed floor.

#define GX 1024
#define GY 1024
#define GZ 40
#define NVOXEL (GX * GY * GZ)                 // 41,943,040
#define MAXV 60000
#define MAXP 32
#define HBITS 21
#define HSIZE (1u << HBITS)
#define HMASK (HSIZE - 1u)
#define CANDBIT (1 << 30)
#define FLATMASK (CANDBIT - 1)
#define TB 256
#define KEARLY 131072
#define NBE (KEARLY / TB)                     // 512 early blocks
#define NBITW (NVOXEL / 32)                   // 1,310,720 bitmap words
#define GRID_BLKS 768                         // cooperative grid (validated R16)
#define NCNT 16                               // barrier sub-counters (768/16=48)
#define BAR_INTS 288                          // per-instance: 16x16 sub + 16 master + 16 gen
#define NBAR 6
#define EMPTY64 0xFFFFFFFFFFFFFFFFull

#define OFF_COORS ((size_t)MAXV * MAXP * 4)            // 7,680,000
#define OFF_NPV   (OFF_COORS + (size_t)MAXV * 3)       // 7,860,000
#define OFF_VNUM  (OFF_NPV + (size_t)MAXV)             // 7,920,000

typedef unsigned long long u64;

__device__ __forceinline__ unsigned hashf(int flat) {
    return ((unsigned)flat * 2654435761u) >> (32 - HBITS);
}

__device__ __forceinline__ int voxel_flat(float4 pt) {
    // identical IEEE f32 math to reference
    float fx = floorf((pt.x + 51.2f) / 0.1f);
    float fy = floorf((pt.y + 51.2f) / 0.1f);
    float fz = floorf((pt.z + 5.0f) / 0.2f);
    int cx = (int)fx, cy = (int)fy, cz = (int)fz;
    bool valid = (fx >= 0.f) & (cx < GX) & (fy >= 0.f) & (cy < GY) & (fz >= 0.f) & (cz < GZ);
    return valid ? (cx * GY + cy) * GZ + cz : -1;
}

// ======== custom two-level grid barrier (leader-thread calls only) ========
// Instance layout (ints): sub[lane*16] (16 lanes, 64B apart), master at
// [256], gen at [272]. Single-use; zeroed by k_init before k_rest launch.
__device__ __forceinline__ bool bar_arrive(int* bi) {
    __threadfence();                                     // agent-release prior writes
    int lane = blockIdx.x & (NCNT - 1);
    int sc = __hip_atomic_fetch_add(&bi[lane * 16], 1, __ATOMIC_ACQ_REL,
                                    __HIP_MEMORY_SCOPE_AGENT) + 1;
    if (sc == (GRID_BLKS / NCNT)) {
        int mc = __hip_atomic_fetch_add(&bi[256], 1, __ATOMIC_ACQ_REL,
                                        __HIP_MEMORY_SCOPE_AGENT) + 1;
        if (mc == NCNT) return true;                     // overall winner
    }
    return false;
}
__device__ __forceinline__ void bar_release(int* bi) {
    __hip_atomic_store(&bi[272], 1, __ATOMIC_RELEASE, __HIP_MEMORY_SCOPE_AGENT);
}
__device__ __forceinline__ void bar_wait(int* bi) {
    // bounded spin: safety-valve against hang (never triggers if logic right)
    for (long sp = 0; sp < (1L << 25); sp++) {
        if (__hip_atomic_load(&bi[272], __ATOMIC_ACQUIRE, __HIP_MEMORY_SCOPE_AGENT))
            return;
        __builtin_amdgcn_s_sleep(4);
    }
}
__device__ __forceinline__ void gbar(int* bi) {
    __syncthreads();
    if (threadIdx.x == 0) {
        if (bar_arrive(bi)) bar_release(bi);
        else bar_wait(bi);
    }
    __syncthreads();
}

// ---- exact insert path (R12 semantics): 1 CAS typ.; returns pflat value ----
__device__ __forceinline__ int build_insert(int p, int flat, u64* __restrict__ h64,
                                            unsigned char* __restrict__ contested,
                                            int* __restrict__ nvox,
                                            unsigned* __restrict__ bitmap,
                                            int count_wins) {
    u64 want = ((u64)(unsigned)flat << 32) | (unsigned)p;
    unsigned slot = hashf(flat);
    int cand = 0, won = 0;
    for (int probe = 0; probe < 4096; probe++) {          // bounded: hang-proof
        u64 cur = atomicCAS(&h64[slot], EMPTY64, want);
        if (cur == EMPTY64) { cand = 1; won = 1; break; } // insert winner (new voxel)
        if ((unsigned)(cur >> 32) == (unsigned)flat) {    // existing voxel
            if ((unsigned)cur > (unsigned)p) {
                u64 old = atomicMin(&h64[slot], want);    // key equal -> compares rep
                unsigned oldrep = (unsigned)old;
                if (oldrep > (unsigned)p) {               // we really lowered it
                    contested[oldrep] = 1;                // previous holder dethroned
                    cand = 1;
                }
            }
            break;
        }
        slot = (slot + 1u) & HMASK;
    }
    if (won) {
        atomicOr(&bitmap[(unsigned)flat >> 5], 1u << (flat & 31));  // voxel present
        if (count_wins) atomicAdd(nvox, 1);               // wave-aggregated
    }
    return flat | (cand ? CANDBIT : 0);
}

// ---- dup registration: flat -> h64 rep -> popcount rank -> dupcnt/list ----
__device__ __forceinline__ void register_dup(int flat, int i,
                                             const u64* __restrict__ h64,
                                             const u64* __restrict__ flagbits,
                                             const int* __restrict__ partials,
                                             int* __restrict__ dupcnt,
                                             int* __restrict__ list) {
    unsigned slot = hashf(flat);
    unsigned rep = 0xFFFFFFFFu;
    for (int probe = 0; probe < 4096; probe++) {     // read-only, cache-hot
        u64 cur = h64[slot];
        if ((unsigned)(cur >> 32) == (unsigned)flat) { rep = (unsigned)cur; break; }
        if (cur == EMPTY64) break;
        slot = (slot + 1u) & HMASK;
    }
    if (rep == 0xFFFFFFFFu) return;
    int br = (int)(rep >> 8);                        // rep's 256-block
    int lb = (int)(rep & 255u);
    int dvid = partials[br];
    int wb = br * 4, nw = lb >> 6;
    for (int q = 0; q < nw; q++) dvid += (int)__popcll(flagbits[wb + q]);
    int tail = lb & 63;
    if (tail) dvid += (int)__popcll(flagbits[wb + nw] & ((1ull << tail) - 1ull));
    if (dvid < MAXV) {
        int pos = atomicAdd(&dupcnt[dvid], 1);
        if (pos < MAXP - 1) list[dvid * (MAXP - 1) + pos] = i;
    }
}

// ---- init (normal launch): h64, bitmap, contested, dupcnt/repidx, coors,
//      partials, nvox/dcnt, AND barrier region ----
__global__ void k_init(u64* __restrict__ h64, unsigned char* __restrict__ contested,
                       int* __restrict__ dupcnt, int* __restrict__ repidx,
                       int n, int nbp, float* __restrict__ oF,
                       int* __restrict__ nvox, unsigned* __restrict__ bitmap,
                       unsigned* __restrict__ dcnt, int* __restrict__ bars) {
    int i = blockIdx.x * blockDim.x + threadIdx.x;
    int stride = gridDim.x * blockDim.x;
    if (i == 0) { *nvox = 0; *dcnt = 0; }
    for (int j = i; j < (int)HSIZE; j += stride) h64[j] = EMPTY64;
    for (int j = i; j < NBITW; j += stride) bitmap[j] = 0u;
    int nw = (n + 3) / 4;
    unsigned* c4 = (unsigned*)contested;
    for (int j = i; j < nw; j += stride) c4[j] = 0;
    for (int j = i; j < MAXV; j += stride) { dupcnt[j] = 0; repidx[j] = -1; }
    for (int j = i; j < MAXV * 3; j += stride) oF[OFF_COORS + j] = 0.f;
    for (int j = i; j < nbp; j += stride) {
        int* p = (int*)dupcnt;  // silence unused warning pattern; real target below
        (void)p;
    }
    for (int j = i; j < nbp; j += stride) ((int*)nullptr, 0);  // no-op
    // partials + barrier region
    // (partials passed via bars-adjacent? no: zero via separate pointer below)
    for (int j = i; j < NBAR * BAR_INTS; j += stride) bars[j] = 0;
}

// partials zeroing split out (kept simple: separate small kernel-free pass in
// k_init would need the pointer; do it here)
__global__ void k_zero_partials(int* __restrict__ partials, int nbp) {
    int i = blockIdx.x * blockDim.x + threadIdx.x;
    if (i < nbp) partials[i] = 0;
}

// =================== fused cooperative kernel (post-init) ===================
__global__ __launch_bounds__(TB, 4) void k_rest(const float4* __restrict__ pts,
                                                int n, int nbp,
                                                u64* __restrict__ h64,
                                                unsigned* __restrict__ bitmap,
                                                unsigned char* __restrict__ contested,
                                                int* __restrict__ pflat,
                                                u64* __restrict__ flagbits,
                                                int* __restrict__ partials,
                                                int* __restrict__ repidx,
                                                int* __restrict__ dupcnt,
                                                int* __restrict__ list,
                                                u64* __restrict__ latedup,
                                                int* __restrict__ nvox,
                                                unsigned* __restrict__ dcnt,
                                                int* __restrict__ bars,
                                                float4* __restrict__ outVox,
                                                float* __restrict__ oF) {
    const int t = threadIdx.x;
    const int gid = blockIdx.x * TB + t;
    const int gsz = GRID_BLKS * TB;
    __shared__ int sh[TB];
    __shared__ int shwin;

    // ---- S1 build_early: first min(n,KEARLY) pts, full insert + bitmap ----
    {
        int nE = n < KEARLY ? n : KEARLY;
        for (int p = gid; p < nE; p += gsz) {
            float4 pt = pts[p];
            int flat = voxel_flat(pt);
            if (flat < 0) { pflat[p] = -1; continue; }
            pflat[p] = build_insert(p, flat, h64, contested, nvox, bitmap, 1);
        }
    }
    gbar(bars + 0 * BAR_INTS);                           // B0

    const bool fast = (*((volatile int*)nvox) >= MAXV);  // grid-uniform after B0
    const int npbF = fast ? (nbp < NBE ? nbp : NBE) : nbp;

    // ---- S2 ----
    if (fast) {
        // late probe: >=MAXV voxels exist with reps < KEARLY <= p, so a voxel
        // first seen here would get vid >= MAXV => dropped. Only dup-of-early
        // matters; bitmap answers membership exactly. No pflat/h64 traffic.
        for (int p = KEARLY + gid; p < n; p += gsz) {
            float4 pt = pts[p];
            int flat = voxel_flat(pt);
            if (flat < 0) continue;
            unsigned wv = bitmap[(unsigned)flat >> 5];
            if (wv & (1u << (flat & 31))) {
                unsigned pos = atomicAdd(dcnt, 1u);
                if (pos < (unsigned)(n - KEARLY))
                    latedup[pos] = ((u64)(unsigned)flat << 32) | (unsigned)p;
            }
        }
        // flags for early point-blocks (late points can never be reps)
        for (int pb = blockIdx.x; pb < npbF; pb += GRID_BLKS) {
            int i = pb * TB + t;
            int pred = 0;
            if (i < n) {
                int pf = pflat[i];
                pred = (pf >= 0) && (pf & CANDBIT) && !contested[i];
            }
            u64 m = __ballot(pred);
            if ((t & 63) == 0) {
                flagbits[pb * 4 + (t >> 6)] = m;
                atomicAdd(&partials[pb], (int)__popcll(m));
            }
        }
    } else {
        // fallback: exact R12 insert for late points, then flags over ALL
        for (int p = KEARLY + gid; p < n; p += gsz) {
            float4 pt = pts[p];
            int flat = voxel_flat(pt);
            if (flat < 0) { pflat[p] = -1; continue; }
            pflat[p] = build_insert(p, flat, h64, contested, nvox, bitmap, 0);
        }
        gbar(bars + 1 * BAR_INTS);                       // B1 (fallback only)
        for (int pb = blockIdx.x; pb < nbp; pb += GRID_BLKS) {
            int i = pb * TB + t;
            int pred = 0;
            if (i < n) {
                int pf = pflat[i];
                pred = (pf >= 0) && (pf & CANDBIT) && !contested[i];
            }
            u64 m = __ballot(pred);
            if ((t & 63) == 0) {
                flagbits[pb * 4 + (t >> 6)] = m;
                atomicAdd(&partials[pb], (int)__popcll(m));
            }
        }
    }

    // ---- B2 + scan-by-winner-block: exclusive prefix over npbF partials ----
    {
        int* bsc = bars + 2 * BAR_INTS;
        __syncthreads();
        if (t == 0) shwin = bar_arrive(bsc) ? 1 : 0;
        __syncthreads();
        if (shwin) {
            int E = (npbF + TB - 1) / TB;                // 2 fast / 19 fallback
            int s = 0;
            for (int k = 0; k < E; k++) {
                int idx = t * E + k;
                if (idx < npbF) s += partials[idx];
            }
            sh[t] = s;
            __syncthreads();
            for (int off = 1; off < TB; off <<= 1) {
                int add = (t >= off) ? sh[t - off] : 0;
                __syncthreads();
                sh[t] += add;
                __syncthreads();
            }
            int run = sh[t] - s;                         // exclusive base
            for (int k = 0; k < E; k++) {
                int idx = t * E + k;
                if (idx < npbF) { int tmp = partials[idx]; partials[idx] = run; run += tmp; }
            }
            if (t == TB - 1) {
                int total = sh[TB - 1];
                if (total > MAXV) total = MAXV;
                oF[OFF_VNUM] = (float)total;             // voxel_num
            }
            __syncthreads();
            if (t == 0) { __threadfence(); bar_release(bsc); }
        } else {
            if (t == 0) bar_wait(bsc);
        }
        __syncthreads();
    }

    // ---- S3 finish: reps->coors/repidx, per-point dups; + latedup drain ----
    for (int pb = blockIdx.x; pb < npbF; pb += GRID_BLKS) {
        int i = pb * TB + t;
        if (i >= n) continue;
        int lane = t & 63, w = t >> 6;
        u64 w0 = flagbits[pb * 4 + 0];
        u64 w1 = flagbits[pb * 4 + 1];
        u64 w2 = flagbits[pb * 4 + 2];
        u64 w3 = flagbits[pb * 4 + 3];
        u64 myw = (w == 0) ? w0 : (w == 1) ? w1 : (w == 2) ? w2 : w3;
        int bit = (int)((myw >> lane) & 1);
        int pf = pflat[i];
        if (bit) {                                       // first occurrence (rep)
            int wbase = (w > 0 ? __popcll(w0) : 0) + (w > 1 ? __popcll(w1) : 0)
                      + (w > 2 ? __popcll(w2) : 0);
            int vid = partials[pb] + wbase + (int)__popcll(myw & ((1ull << lane) - 1ull));
            if (vid < MAXV) {
                int flat = pf & FLATMASK;
                int zc = flat % GZ;
                int t2 = flat / GZ;
                int yc = t2 % GY;
                int xc = t2 / GY;
                size_t cOff = OFF_COORS + (size_t)vid * 3;
                oF[cOff + 0] = (float)zc;
                oF[cOff + 1] = (float)yc;
                oF[cOff + 2] = (float)xc;
                repidx[vid] = i;
            }
        } else if (pf >= 0) {                            // non-rep valid
            register_dup(pf & FLATMASK, i, h64, flagbits, partials, dupcnt, list);
        }
    }
    {
        unsigned cnt = *((volatile unsigned*)dcnt);      // 0 in fallback
        unsigned cap = (n > KEARLY) ? (unsigned)(n - KEARLY) : 0u;
        if (cnt > cap) cnt = cap;
        for (unsigned idx = (unsigned)gid; idx < cnt; idx += (unsigned)gsz) {
            u64 e = latedup[idx];
            register_dup((int)(e >> 32), (int)(unsigned)e,
                         h64, flagbits, partials, dupcnt, list);
        }
    }
    gbar(bars + 3 * BAR_INTS);                           // B3

    // ---- S4 emit: thread-per-row, fully coalesced voxels store; npv ----
    for (int g2 = gid; g2 < MAXV * MAXP; g2 += gsz) {
        int vid = g2 >> 5;
        int r = g2 & 31;
        int ri = repidx[vid];
        int dc = dupcnt[vid];
        int d = dc < (MAXP - 1) ? dc : (MAXP - 1);
        int m = (ri >= 0) ? (1 + d) : 0;
        if (r == 0) oF[OFF_NPV + vid] = (float)m;
        float4 row = make_float4(0.f, 0.f, 0.f, 0.f);
        if (r == 0 && m > 0) {
            row = pts[ri];                               // rep = provably min index
        } else if (r < m) {                              // dup rows, ascending index
            const int* lst = &list[vid * (MAXP - 1)];
            int target = r - 1, pick = -1;
            for (int a = 0; a < d; a++) {
                int e = lst[a];
                int rk = 0;
                for (int bq = 0; bq < d; bq++) rk += (lst[bq] < e);
                if (rk == target) pick = e;
            }
            row = pts[pick];
        }
        outVox[(size_t)vid * MAXP + r] = row;            // coalesced 16B stores
    }
}

// =================== legacy multi-kernel fallback path ===================
__global__ __launch_bounds__(TB) void k_build_early(const float4* __restrict__ pts, int nE,
                                                    u64* __restrict__ h64,
                                                    int* __restrict__ pflat,
                                                    unsigned char* __restrict__ contested,
                                                    int* __restrict__ nvox,
                                                    unsigned* __restrict__ bitmap) {
    int p = blockIdx.x * blockDim.x + threadIdx.x;
    if (p >= nE) return;
    float4 pt = pts[p];
    int flat = voxel_flat(pt);
    if (flat < 0) { pflat[p] = -1; return; }
    pflat[p] = build_insert(p, flat, h64, contested, nvox, bitmap, 1);
}

__global__ __launch_bounds__(TB) void k_build_late(const float4* __restrict__ pts, int n,
                                                   u64* __restrict__ h64,
                                                   int* __restrict__ pflat,
                                                   unsigned char* __restrict__ contested,
                                                   int* __restrict__ nvox,
                                                   unsigned* __restrict__ bitmap,
                                                   u64* __restrict__ latedup,
                                                   unsigned* __restrict__ dcnt) {
    int p = KEARLY + blockIdx.x * blockDim.x + threadIdx.x;
    if (p >= n) return;
    float4 pt = pts[p];
    int flat = voxel_flat(pt);
    if (*nvox < MAXV) {
        if (flat < 0) { pflat[p] = -1; return; }
        pflat[p] = build_insert(p, flat, h64, contested, nvox, bitmap, 0);
        return;
    }
    if (flat < 0) return;
    unsigned w = bitmap[(unsigned)flat >> 5];
    if (w & (1u << (flat & 31))) {
        unsigned pos = atomicAdd(dcnt, 1u);
        if (pos < (unsigned)(n - KEARLY))
            latedup[pos] = ((u64)(unsigned)flat << 32) | (unsigned)p;
    }
}

__global__ __launch_bounds__(TB) void k_flags(const int* __restrict__ pflat,
                                              const unsigned char* __restrict__ contested,
                                              int n, u64* __restrict__ flagbits,
                                              int* __restrict__ partials,
                                              const int* __restrict__ nvox) {
    __shared__ int ws[4];
    int b = blockIdx.x, t = threadIdx.x;
    int i = b * TB + t;
    int fastmode = (*nvox >= MAXV);
    int pred = 0;
    if (i < n && (b < NBE || !fastmode)) {
        int pf = pflat[i];
        pred = (pf >= 0) && (pf & CANDBIT) && !contested[i];
    }
    u64 m = __ballot(pred);
    int w = t >> 6, lane = t & 63;
    if (lane == 0) { flagbits[b * 4 + w] = m; ws[w] = __popcll(m); }
    __syncthreads();
    if (t == 0) partials[b] = ws[0] + ws[1] + ws[2] + ws[3];
}

__global__ __launch_bounds__(1024) void k_scan(int* __restrict__ partials, int npart,
                                               float* __restrict__ oF) {
    __shared__ int sh[1024];
    int t = threadIdx.x;
    int v[5];
    int s = 0;
    #pragma unroll
    for (int k = 0; k < 5; k++) {
        int idx = t * 5 + k;
        v[k] = (idx < npart) ? partials[idx] : 0;
        s += v[k];
    }
    sh[t] = s;
    __syncthreads();
    for (int off = 1; off < 1024; off <<= 1) {
        int add = (t >= off) ? sh[t - off] : 0;
        __syncthreads();
        sh[t] += add;
        __syncthreads();
    }
    int run = sh[t] - s;
    #pragma unroll
    for (int k = 0; k < 5; k++) {
        int idx = t * 5 + k;
        if (idx < npart) partials[idx] = run;
        run += v[k];
    }
    if (t == 1023) {
        int total = sh[1023];
        if (total > MAXV) total = MAXV;
        oF[OFF_VNUM] = (float)total;
    }
}

__global__ __launch_bounds__(TB) void k_finish(const u64* __restrict__ flagbits,
                                               const int* __restrict__ partials,
                                               const int* __restrict__ pflat,
                                               const u64* __restrict__ h64,
                                               int* __restrict__ repidx,
                                               int* __restrict__ dupcnt,
                                               int* __restrict__ list, int n,
                                               float* __restrict__ oF,
                                               const int* __restrict__ nvox,
                                               const u64* __restrict__ latedup,
                                               const unsigned* __restrict__ dcnt) {
    int b = blockIdx.x, t = threadIdx.x;
    int fastmode = (*nvox >= MAXV);
    if (fastmode && b >= NBE) {
        unsigned cnt = *dcnt;
        unsigned cap = (unsigned)(n - KEARLY);
        if (cnt > cap) cnt = cap;
        unsigned idx = (unsigned)(b - NBE) * TB + t;
        if (idx < cnt) {
            u64 e = latedup[idx];
            register_dup((int)(e >> 32), (int)(unsigned)e,
                         h64, flagbits, partials, dupcnt, list);
        }
        return;
    }
    int i = b * TB + t;
    if (i >= n) return;
    int lane = t & 63, w = t >> 6;
    u64 w0 = flagbits[b * 4 + 0];
    u64 w1 = flagbits[b * 4 + 1];
    u64 w2 = flagbits[b * 4 + 2];
    u64 w3 = flagbits[b * 4 + 3];
    u64 myw = (w == 0) ? w0 : (w == 1) ? w1 : (w == 2) ? w2 : w3;
    int bit = (int)((myw >> lane) & 1);
    int pf = pflat[i];
    if (bit) {
        int wbase = (w > 0 ? __popcll(w0) : 0) + (w > 1 ? __popcll(w1) : 0)
                  + (w > 2 ? __popcll(w2) : 0);
        int vid = partials[b] + wbase + (int)__popcll(myw & ((1ull << lane) - 1ull));
        if (vid < MAXV) {
            int flat = pf & FLATMASK;
            int zc = flat % GZ;
            int t2 = flat / GZ;
            int yc = t2 % GY;
            int xc = t2 / GY;
            size_t cOff = OFF_COORS + (size_t)vid * 3;
            oF[cOff + 0] = (float)zc;
            oF[cOff + 1] = (float)yc;
            oF[cOff + 2] = (float)xc;
            repidx[vid] = i;
        }
    } else if (pf >= 0) {
        register_dup(pf & FLATMASK, i, h64, flagbits, partials, dupcnt, list);
    }
}

__global__ __launch_bounds__(TB) void k_emit(const float4* __restrict__ pts,
                                             const int* __restrict__ repidx,
                                             const int* __restrict__ dupcnt,
                                             const int* __restrict__ list,
                                             float4* __restrict__ outVox,
                                             float* __restrict__ oF) {
    int gid = blockIdx.x * TB + threadIdx.x;
    int vid = gid >> 5;
    if (vid >= MAXV) return;
    int r = gid & 31;
    int ri = repidx[vid];
    int dc = dupcnt[vid];
    int d = dc < (MAXP - 1) ? dc : (MAXP - 1);
    int m = (ri >= 0) ? (1 + d) : 0;
    if (r == 0) oF[OFF_NPV + vid] = (float)m;
    float4 row = make_float4(0.f, 0.f, 0.f, 0.f);
    if (r == 0 && m > 0) {
        row = pts[ri];
    } else if (r < m) {
        const int* lst = &list[vid * (MAXP - 1)];
        int target = r - 1, pick = -1;
        for (int a = 0; a < d; a++) {
            int e = lst[a];
            int rk = 0;
            for (int bq = 0; bq < d; bq++) rk += (lst[bq] < e);
            if (rk == target) pick = e;
        }
        row = pts[pick];
    }
    outVox[(size_t)vid * MAXP + r] = row;
}

extern "C" void kernel_launch(void* const* d_in, const int* in_sizes, int n_in,
                              void* d_out, int out_size, void* d_ws, size_t ws_size,
                              hipStream_t stream) {
    int n = in_sizes[0] / 4;                       // 1,200,000
    const float4* pts = (const float4*)d_in[0];

    int tb = TB;
    int nbp = (n + tb - 1) / tb;                   // 4688
    int nwords = nbp * 4;

    // ws layout, ~45 MB
    char* base = (char*)d_ws;
    size_t o = 0;
    int* partials = (int*)(base + o);  o += ((size_t)nbp * 4 + 255) & ~(size_t)255;
    int* dupcnt   = (int*)(base + o);  o += (size_t)MAXV * 4;
    int* repidx   = (int*)(base + o);  o += (size_t)MAXV * 4;
    o = (o + 255) & ~(size_t)255;
    u64* flagbits = (u64*)(base + o);  o += (size_t)nwords * 8;
    o = (o + 255) & ~(size_t)255;
    unsigned char* contested = (unsigned char*)(base + o);  o += ((size_t)n + 255) & ~(size_t)255;
    u64* h64      = (u64*)(base + o);  o += (size_t)HSIZE * 8;
    int* pflat    = (int*)(base + o);  o += (size_t)n * 4;
    int* list     = (int*)(base + o);  o += (size_t)MAXV * (MAXP - 1) * 4;
    o = (o + 255) & ~(size_t)255;
    unsigned* bitmap = (unsigned*)(base + o);  o += (size_t)NBITW * 4;
    o = (o + 255) & ~(size_t)255;
    u64* latedup  = (u64*)(base + o);  o += (size_t)(n > KEARLY ? n - KEARLY : 1) * 8;
    o = (o + 255) & ~(size_t)255;
    int* nvox     = (int*)(base + o);  o += 256;
    unsigned* dcnt = (unsigned*)(base + o);  o += 256;
    int* bars     = (int*)(base + o);  o += ((size_t)NBAR * BAR_INTS * 4 + 255) & ~(size_t)255;

    float* oF = (float*)d_out;
    float4* outVox = (float4*)d_out;

    // dispatch 1: init (also zeroes barrier region)
    k_init<<<2048, tb, 0, stream>>>(h64, contested, dupcnt, repidx, n, nbp, oF,
                                    nvox, bitmap, dcnt, bars);
    k_zero_partials<<<(nbp + tb - 1) / tb, tb, 0, stream>>>(partials, nbp);

    // dispatch 2: fused cooperative remainder (3 custom barriers fast mode)
    void* args[] = { (void*)&pts, (void*)&n, (void*)&nbp, (void*)&h64,
                     (void*)&bitmap, (void*)&contested, (void*)&pflat,
                     (void*)&flagbits, (void*)&partials, (void*)&repidx,
                     (void*)&dupcnt, (void*)&list, (void*)&latedup,
                     (void*)&nvox, (void*)&dcnt, (void*)&bars,
                     (void*)&outVox, (void*)&oF };
    hipError_t err = hipLaunchCooperativeKernel((const void*)k_rest,
                                                dim3(GRID_BLKS), dim3(TB),
                                                args, 0, stream);
    if (err == hipSuccess) return;

    // fallback: proven R15 multi-kernel pipeline (init already ran)
    int nE = n < KEARLY ? n : KEARLY;
    int nbE = (nE + tb - 1) / tb;
    int nL = n - nE;

    k_build_early<<<nbE, tb, 0, stream>>>(pts, nE, h64, pflat, contested, nvox, bitmap);
    if (nL > 0)
        k_build_late<<<(nL + tb - 1) / tb, tb, 0, stream>>>(pts, n, h64, pflat,
                                                            contested, nvox, bitmap,
                                                            latedup, dcnt);
    k_flags<<<nbp, tb, 0, stream>>>(pflat, contested, n, flagbits, partials, nvox);
    k_scan<<<1, 1024, 0, stream>>>(partials, nbp, oF);
    k_finish<<<nbp, tb, 0, stream>>>(flagbits, partials, pflat, h64, repidx, dupcnt,
                                     list, n, oF, nvox, latedup, dcnt);
    k_emit<<<(MAXV * MAXP + tb - 1) / tb, tb, 0, stream>>>(pts, repidx, dupcnt, list,
                                                           outVox, oF);
}